// Round 3
// baseline (20077.309 us; speedup 1.0000x reference)
//
#include <hip/hip_runtime.h>
#include <hip/hip_bf16.h>
#include <cstdint>
#include <cstddef>

typedef __attribute__((ext_vector_type(8))) __bf16 bf16x8;
typedef __attribute__((ext_vector_type(4))) float floatx4;

__device__ __forceinline__ floatx4 mfma16(bf16x8 a, bf16x8 b, floatx4 c) {
  return __builtin_amdgcn_mfma_f32_16x16x32_bf16(a, b, c, 0, 0, 0);
}

// tanh(x) = 1 - 2/(exp(2x)+1); exp(+inf)->inf -> 2/inf=0 -> +1; exp(-inf)->0 -> -1. NaN-free for finite x.
__device__ __forceinline__ float tanh_fast(float x) {
  float e = __expf(2.0f * x);
  return 1.0f - 2.0f / (e + 1.0f);
}

// ---------------------------------------------------------------------------
// k_cvt: fp32 -> bf16, 8 elems/thread, grid-stride. n8 = count/8 (count % 8 == 0).
// ---------------------------------------------------------------------------
__global__ __launch_bounds__(256) void k_cvt(const float* __restrict__ src,
                                             __bf16* __restrict__ dst, int n8) {
  int i = blockIdx.x * 256 + threadIdx.x;
  const int stride = gridDim.x * 256;
  for (; i < n8; i += stride) {
    const float4* s = (const float4*)(src + (size_t)i * 8);
    float4 a = s[0], b = s[1];
    bf16x8 v;
    v[0] = (__bf16)a.x; v[1] = (__bf16)a.y; v[2] = (__bf16)a.z; v[3] = (__bf16)a.w;
    v[4] = (__bf16)b.x; v[5] = (__bf16)b.y; v[6] = (__bf16)b.z; v[7] = (__bf16)b.w;
    *(bf16x8*)(dst + (size_t)i * 8) = v;
  }
}

// ---------------------------------------------------------------------------
// k_rnn: 1024 steps, persistent, 64 blocks x 256 thr (co-resident: 64 << 256 CUs).
// Monotonic-counter grid barrier, split-phase: x-part (K=512, no h dep) runs
// before the wait and hides other blocks' step-(t-1) tail.
// wg = 2 m-groups(64 rows) x 32 n-groups(32 cols); wave: 32 rows x 16 cols.
// A layout: A[m=lane&15][k=quad*8+j]; B: B[n=lane&15][k=quad*8+j];
// C/D: col=lane&15, row=quad*4+r  [m89/m120-verified].
// ---------------------------------------------------------------------------
__global__ __launch_bounds__(256) void k_rnn(
    const __bf16* __restrict__ xb,      // [128][1024][512] bf16 (pre-converted)
    const __bf16* __restrict__ wihb,    // [1024][1536] bf16
    const float*  __restrict__ bih,     // [1024] fp32
    __bf16* __restrict__ h0,
    __bf16* __restrict__ h1,
    unsigned* __restrict__ cnt)
{
  const int tid  = threadIdx.x;
  const int lane = tid & 63;
  const int w    = tid >> 6;
  const int wg   = blockIdx.x;                // 0..63
  const int row0 = (wg >> 5) * 64 + (w >> 1) * 32;  // rows row0..row0+31 (2 tiles)
  const int col0 = (wg & 31) * 32 + (w & 1) * 16;   // cols col0..col0+15
  const int lm   = lane & 15;
  const int qk   = (lane >> 4) * 8;

  const int n = col0 + lm;
  const __bf16* bxp = wihb + (size_t)n * 1536 + qk;   // Wx row n
  const __bf16* bhp = bxp + 512;                      // Wh row n
  const float bias = bih[n];

  const __bf16* xr0 = xb + (size_t)(row0 + lm) * 524288 + qk;
  const __bf16* xr1 = xr0 + 16 * 524288;

  for (int t = 0; t < 1024; ++t) {
    floatx4 acc0 = {0.f, 0.f, 0.f, 0.f};
    floatx4 acc1 = {0.f, 0.f, 0.f, 0.f};

    // ---- x-part: x_t @ Wx^T (independent of h)
    {
      const __bf16* xa0 = xr0 + (size_t)t * 512;
      const __bf16* xa1 = xr1 + (size_t)t * 512;
#pragma unroll 4
      for (int kk = 0; kk < 16; ++kk) {
        bf16x8 b  = *(const bf16x8*)(bxp + kk * 32);
        bf16x8 a0 = *(const bf16x8*)(xa0 + kk * 32);
        bf16x8 a1 = *(const bf16x8*)(xa1 + kk * 32);
        acc0 = mfma16(a0, b, acc0);
        acc1 = mfma16(a1, b, acc1);
      }
    }

    // ---- wait for h_t, then h-part: h_t @ Wh^T
    if (t > 0) {
      if (tid == 0) {
        const unsigned target = (unsigned)t * 64u;
        while (__hip_atomic_load(cnt, __ATOMIC_RELAXED, __HIP_MEMORY_SCOPE_AGENT) < target)
          __builtin_amdgcn_s_sleep(2);
        __threadfence();   // acquire: inv L1 + XCD L2 before reading remote h
      }
      __syncthreads();

      const __bf16* hc  = (t & 1) ? h1 : h0;   // h_t
      const __bf16* ap0 = hc + (size_t)(row0 + lm) * 1024 + qk;
      const __bf16* ap1 = ap0 + 16 * 1024;
#pragma unroll 8
      for (int kk = 0; kk < 32; ++kk) {
        bf16x8 b  = *(const bf16x8*)(bhp + kk * 32);
        bf16x8 a0 = *(const bf16x8*)(ap0 + kk * 32);
        bf16x8 a1 = *(const bf16x8*)(ap1 + kk * 32);
        acc0 = mfma16(a0, b, acc0);
        acc1 = mfma16(a1, b, acc1);
      }
    }

    // ---- tanh + write h_{t+1}
    __bf16* hn = (t & 1) ? h0 : h1;
#pragma unroll
    for (int r = 0; r < 4; ++r) {
      const int m0 = row0 + (lane >> 4) * 4 + r;
      const int m1 = m0 + 16;
      hn[(size_t)m0 * 1024 + n] = (__bf16)tanh_fast(acc0[r] + bias);
      hn[(size_t)m1 * 1024 + n] = (__bf16)tanh_fast(acc1[r] + bias);
    }

    // ---- signal: stores drained by the vmcnt(0) before s_barrier; wbL2 via fence
    __syncthreads();
    if (tid == 0) {
      __threadfence();     // release: write back XCD L2
      atomicAdd(cnt, 1u);  // device-scope
    }
  }
  // final h_1024 in h0 (t=1023 writes hn=h0)
}

// ---------------------------------------------------------------------------
// k_out: y = h_final @ W_ho^T + b_ho (fp32 out). 32 blocks x 4 waves.
// ---------------------------------------------------------------------------
__global__ __launch_bounds__(256) void k_out(
    const __bf16* __restrict__ hfin,
    const __bf16* __restrict__ whob,    // [512][1024] bf16
    const float*  __restrict__ bho,     // [512] fp32
    float* __restrict__ y)              // [128][512] fp32
{
  const int tid  = threadIdx.x;
  const int lane = tid & 63;
  const int w    = tid >> 6;
  const int col0 = blockIdx.x * 16;
  const int row0 = w * 32;
  const int lm   = lane & 15;
  const int qk   = (lane >> 4) * 8;

  floatx4 acc0 = {0.f, 0.f, 0.f, 0.f};
  floatx4 acc1 = {0.f, 0.f, 0.f, 0.f};
  const __bf16* bp = whob + (size_t)(col0 + lm) * 1024 + qk;
  const __bf16* a0 = hfin + (size_t)(row0 + lm) * 1024 + qk;
  const __bf16* a1 = a0 + 16 * 1024;
#pragma unroll 8
  for (int kk = 0; kk < 32; ++kk) {
    bf16x8 b = *(const bf16x8*)(bp + kk * 32);
    acc0 = mfma16(*(const bf16x8*)(a0 + kk * 32), b, acc0);
    acc1 = mfma16(*(const bf16x8*)(a1 + kk * 32), b, acc1);
  }
  const int nn = col0 + lm;
  const float bias = bho[nn];
#pragma unroll
  for (int r = 0; r < 4; ++r) {
    const int m0 = row0 + (lane >> 4) * 4 + r;
    const int m1 = m0 + 16;
    y[(size_t)m0 * 512 + nn] = acc0[r] + bias;
    y[(size_t)m1 * 512 + nn] = acc1[r] + bias;
  }
}

extern "C" void kernel_launch(void* const* d_in, const int* in_sizes, int n_in,
                              void* d_out, int out_size, void* d_ws, size_t ws_size,
                              hipStream_t stream) {
  const float* x   = (const float*)d_in[0];   // [128][1024][512] fp32
  const float* wih = (const float*)d_in[1];   // [1024][1536] fp32
  const float* bih = (const float*)d_in[2];   // [1024] fp32
  const float* who = (const float*)d_in[3];   // [512][1024] fp32
  const float* bho = (const float*)d_in[4];   // [512] fp32
  float* y = (float*)d_out;                   // [128][512] fp32

  // ws layout (bytes): xb 134,217,728 | wihb 3,145,728 | whob 1,048,576 |
  //                    h0 262,144 | h1 262,144 | cnt 64    (total ~138.9 MB)
  char* p = (char*)d_ws;
  __bf16* xb   = (__bf16*)p;
  __bf16* wihb = (__bf16*)(p + 134217728ull);
  __bf16* whob = (__bf16*)(p + 137363456ull);
  __bf16* h0   = (__bf16*)(p + 138412032ull);
  __bf16* h1   = (__bf16*)(p + 138674176ull);
  unsigned* cnt = (unsigned*)(p + 138936320ull);

  hipMemsetAsync(cnt, 0, 64, stream);

  k_cvt<<<dim3(2048), dim3(256), 0, stream>>>(x,   xb,   67108864 / 8);
  k_cvt<<<dim3(512),  dim3(256), 0, stream>>>(wih, wihb, 1572864 / 8);
  k_cvt<<<dim3(256),  dim3(256), 0, stream>>>(who, whob, 524288 / 8);

  k_rnn<<<dim3(64), dim3(256), 0, stream>>>(xb, wihb, bih, h0, h1, cnt);
  k_out<<<dim3(32), dim3(256), 0, stream>>>(h0, whob, bho, y);
}

// Round 4
// 12457.820 us; speedup vs baseline: 1.6116x; 1.6116x over previous
//
#include <hip/hip_runtime.h>
#include <hip/hip_bf16.h>
#include <cstdint>
#include <cstddef>

typedef __attribute__((ext_vector_type(8))) __bf16 bf16x8;
typedef __attribute__((ext_vector_type(4))) float floatx4;

__device__ __forceinline__ floatx4 mfma16(bf16x8 a, bf16x8 b, floatx4 c) {
  return __builtin_amdgcn_mfma_f32_16x16x32_bf16(a, b, c, 0, 0, 0);
}

__device__ __forceinline__ float tanh_fast(float x) {
  float e = __expf(2.0f * x);
  return 1.0f - 2.0f / (e + 1.0f);
}

// Coherent (MALL-level) bf16 store: sc0 sc1 = write-through past L1/L2.
// Cross-XCD visibility then needs only a vmcnt(0) drain, no cache fence.
__device__ __forceinline__ void store_coh_bf16(__bf16* p, float f) {
  unsigned v = (unsigned)__builtin_bit_cast(unsigned short, (__bf16)f);
  asm volatile("global_store_short %0, %1, off sc0 sc1" :: "v"(p), "v"(v));
}

// Issue 4 coherent 16B loads (no wait). Outputs are NOT valid until a later
// vmcnt(0); callers must pass them through coh_wait() before use.
__device__ __forceinline__ void coh_load4(const char* p, bf16x8& a, bf16x8& b,
                                          bf16x8& c, bf16x8& d) {
  asm volatile(
      "global_load_dwordx4 %0, %4, off offset:-4096 sc0 sc1\n\t"
      "global_load_dwordx4 %1, %4, off sc0 sc1\n\t"
      "global_load_dwordx4 %2, %5, off offset:-4096 sc0 sc1\n\t"
      "global_load_dwordx4 %3, %5, off sc0 sc1"
      : "=v"(a), "=v"(b), "=v"(c), "=v"(d)
      : "v"(p), "v"(p + 8192)
      : "memory");
}

// Barrier for the in-flight coherent loads: ties the values through, so any
// consumer of the (possibly renamed) outputs is ordered after the vmcnt.
__device__ __forceinline__ void coh_wait8(bf16x8& a, bf16x8& b, bf16x8& c, bf16x8& d,
                                          bf16x8& e, bf16x8& f, bf16x8& g, bf16x8& h) {
  asm volatile("s_waitcnt vmcnt(0)"
               : "+v"(a), "+v"(b), "+v"(c), "+v"(d),
                 "+v"(e), "+v"(f), "+v"(g), "+v"(h)
               :
               : "memory");
}

// ---------------------------------------------------------------------------
__global__ __launch_bounds__(256) void k_cvt(const float* __restrict__ src,
                                             __bf16* __restrict__ dst, int n8) {
  int i = blockIdx.x * 256 + threadIdx.x;
  const int stride = gridDim.x * 256;
  for (; i < n8; i += stride) {
    const float4* s = (const float4*)(src + (size_t)i * 8);
    float4 a = s[0], b = s[1];
    bf16x8 v;
    v[0] = (__bf16)a.x; v[1] = (__bf16)a.y; v[2] = (__bf16)a.z; v[3] = (__bf16)a.w;
    v[4] = (__bf16)b.x; v[5] = (__bf16)b.y; v[6] = (__bf16)b.z; v[7] = (__bf16)b.w;
    *(bf16x8*)(dst + (size_t)i * 8) = v;
  }
}

// ---------------------------------------------------------------------------
// k_rnn: 4 independent row-groups (32 rows each; batch rows are independent
// recurrences) x 16 col-blocks (64 cols) = 64 blocks, 1/CU, co-resident.
// Per-group 16-participant monotonic barrier. NO cache fences: h is exchanged
// exclusively via sc0 sc1 accesses (MALL-coherent), so Wx/Wh/x stay
// L2-resident across all 1024 steps.
// ---------------------------------------------------------------------------
__global__ __launch_bounds__(256) void k_rnn(
    const __bf16* __restrict__ xb,      // [128][1024][512]
    const __bf16* __restrict__ wihb,    // [1024][1536]
    const float*  __restrict__ bih,     // [1024]
    __bf16* __restrict__ h0,
    __bf16* __restrict__ h1,
    unsigned* __restrict__ cnt)
{
  __shared__ __bf16 hs[32 * 1032];      // 32 rows x (1024 + 8 pad) = 66 KB

  const int tid  = threadIdx.x;
  const int lane = tid & 63;
  const int w    = tid >> 6;
  const int g    = blockIdx.x >> 4;     // group: rows g*32..+31
  const int cb   = blockIdx.x & 15;     // col-block: cols cb*64..+63
  const int lm   = lane & 15;
  const int q    = lane >> 4;
  const int qk   = q * 8;
  const int wc   = cb * 64 + w * 16;    // wave col base (4 waves x 16 cols)
  const int n    = wc + lm;
  const int r0   = g * 32;

  const __bf16* bxp = wihb + (size_t)n * 1536 + qk;   // Wx row n
  const __bf16* bhp = bxp + 512;                      // Wh row n
  const float bias = bih[n];
  unsigned* ct = cnt + g * 16;

  const __bf16* xr0 = xb + (size_t)(r0 + lm) * 524288 + qk;
  const __bf16* xr1 = xr0 + 16ull * 524288;

  // staging geometry: chunk c (0..15) = bytes [tid*16 + c*4096] of the group's
  // 64 KB h-slice -> LDS row 2c + (tid>>7), col (tid&127)*8. Per-instruction
  // lanes are 16B-contiguous (fully coalesced); LDS writes 2-way (free).
  __bf16* sdst = hs + (tid >> 7) * 1032 + (tid & 127) * 8;

  for (int t = 0; t < 1024; ++t) {
    floatx4 acc0 = {0.f, 0.f, 0.f, 0.f};
    floatx4 acc1 = {0.f, 0.f, 0.f, 0.f};

    // ---- x-part: x_t @ Wx^T (no h dependency; fills the pre-barrier window)
    {
      const __bf16* xa0 = xr0 + (size_t)t * 512;
      const __bf16* xa1 = xr1 + (size_t)t * 512;
#pragma unroll 4
      for (int kk = 0; kk < 16; ++kk) {
        bf16x8 b = *(const bf16x8*)(bxp + kk * 32);
        acc0 = mfma16(*(const bf16x8*)(xa0 + kk * 32), b, acc0);
        acc1 = mfma16(*(const bf16x8*)(xa1 + kk * 32), b, acc1);
      }
    }

    if (t > 0) {
      // ---- wait: all 16 blocks of this group finished step t-1
      if (tid == 0) {
        const unsigned target = (unsigned)t * 16u;
        while (__hip_atomic_load(ct, __ATOMIC_RELAXED, __HIP_MEMORY_SCOPE_AGENT) < target)
          __builtin_amdgcn_s_sleep(1);
      }
      __syncthreads();

      // ---- stage h_t rows r0..r0+31 -> LDS (coherent, bulk-issued)
      {
        const __bf16* hc = (t & 1) ? h1 : h0;
        const char* base = (const char*)(hc + (size_t)r0 * 1024) + tid * 16 + 4096;
        bf16x8 s0,s1,s2,s3,s4,s5,s6,s7,s8,s9,s10,s11,s12,s13,s14,s15;
        coh_load4(base,         s0, s1, s2, s3);     // chunks 0..3
        coh_load4(base + 16384, s4, s5, s6, s7);     // chunks 4..7
        coh_load4(base + 32768, s8, s9, s10, s11);   // chunks 8..11
        coh_load4(base + 49152, s12, s13, s14, s15); // chunks 12..15
        coh_wait8(s0, s1, s2, s3, s4, s5, s6, s7);
        coh_wait8(s8, s9, s10, s11, s12, s13, s14, s15);
        *(bf16x8*)(sdst +  0 * 2064) = s0;  *(bf16x8*)(sdst +  1 * 2064) = s1;
        *(bf16x8*)(sdst +  2 * 2064) = s2;  *(bf16x8*)(sdst +  3 * 2064) = s3;
        *(bf16x8*)(sdst +  4 * 2064) = s4;  *(bf16x8*)(sdst +  5 * 2064) = s5;
        *(bf16x8*)(sdst +  6 * 2064) = s6;  *(bf16x8*)(sdst +  7 * 2064) = s7;
        *(bf16x8*)(sdst +  8 * 2064) = s8;  *(bf16x8*)(sdst +  9 * 2064) = s9;
        *(bf16x8*)(sdst + 10 * 2064) = s10; *(bf16x8*)(sdst + 11 * 2064) = s11;
        *(bf16x8*)(sdst + 12 * 2064) = s12; *(bf16x8*)(sdst + 13 * 2064) = s13;
        *(bf16x8*)(sdst + 14 * 2064) = s14; *(bf16x8*)(sdst + 15 * 2064) = s15;
      }
      __syncthreads();

      // ---- h-part: h_t @ Wh^T, A from LDS (2-way bank aliasing only)
#pragma unroll 8
      for (int kk = 0; kk < 32; ++kk) {
        bf16x8 b  = *(const bf16x8*)(bhp + kk * 32);
        bf16x8 a0 = *(const bf16x8*)(hs + lm * 1032 + kk * 32 + qk);
        bf16x8 a1 = *(const bf16x8*)(hs + (16 + lm) * 1032 + kk * 32 + qk);
        acc0 = mfma16(a0, b, acc0);
        acc1 = mfma16(a1, b, acc1);
      }
    }

    // ---- tanh + coherent h_{t+1} stores (C/D: col=lane&15, row=q*4+r)
    {
      __bf16* hn = (t & 1) ? h0 : h1;
#pragma unroll
      for (int r = 0; r < 4; ++r) {
        const int m0 = r0 + q * 4 + r;
        store_coh_bf16(hn + (size_t)m0 * 1024 + n, tanh_fast(acc0[r] + bias));
        store_coh_bf16(hn + (size_t)(m0 + 16) * 1024 + n, tanh_fast(acc1[r] + bias));
      }
    }
    asm volatile("s_waitcnt vmcnt(0)" ::: "memory");  // drain coherent stores
    __syncthreads();                                  // all waves drained
    if (tid == 0)
      __hip_atomic_fetch_add(ct, 1u, __ATOMIC_RELAXED, __HIP_MEMORY_SCOPE_AGENT);
  }
  // h_1024 in h0 (t=1023 writes hn=h0); visible to k_out via dispatch boundary
}

// ---------------------------------------------------------------------------
__global__ __launch_bounds__(256) void k_out(
    const __bf16* __restrict__ hfin,
    const __bf16* __restrict__ whob,
    const float*  __restrict__ bho,
    float* __restrict__ y)
{
  const int tid  = threadIdx.x;
  const int lane = tid & 63;
  const int w    = tid >> 6;
  const int col0 = blockIdx.x * 16;
  const int row0 = w * 32;
  const int lm   = lane & 15;
  const int qk   = (lane >> 4) * 8;

  floatx4 acc0 = {0.f, 0.f, 0.f, 0.f};
  floatx4 acc1 = {0.f, 0.f, 0.f, 0.f};
  const __bf16* bp = whob + (size_t)(col0 + lm) * 1024 + qk;
  const __bf16* a0 = hfin + (size_t)(row0 + lm) * 1024 + qk;
  const __bf16* a1 = a0 + 16 * 1024;
#pragma unroll 8
  for (int kk = 0; kk < 32; ++kk) {
    bf16x8 b = *(const bf16x8*)(bp + kk * 32);
    acc0 = mfma16(*(const bf16x8*)(a0 + kk * 32), b, acc0);
    acc1 = mfma16(*(const bf16x8*)(a1 + kk * 32), b, acc1);
  }
  const int nn = col0 + lm;
  const float bias = bho[nn];
#pragma unroll
  for (int r = 0; r < 4; ++r) {
    const int m0 = row0 + (lane >> 4) * 4 + r;
    const int m1 = m0 + 16;
    y[(size_t)m0 * 512 + nn] = acc0[r] + bias;
    y[(size_t)m1 * 512 + nn] = acc1[r] + bias;
  }
}

extern "C" void kernel_launch(void* const* d_in, const int* in_sizes, int n_in,
                              void* d_out, int out_size, void* d_ws, size_t ws_size,
                              hipStream_t stream) {
  const float* x   = (const float*)d_in[0];
  const float* wih = (const float*)d_in[1];
  const float* bih = (const float*)d_in[2];
  const float* who = (const float*)d_in[3];
  const float* bho = (const float*)d_in[4];
  float* y = (float*)d_out;

  char* p = (char*)d_ws;
  __bf16* xb   = (__bf16*)p;                       // 134,217,728 B
  __bf16* wihb = (__bf16*)(p + 134217728ull);      //   3,145,728 B
  __bf16* whob = (__bf16*)(p + 137363456ull);      //   1,048,576 B
  __bf16* h0   = (__bf16*)(p + 138412032ull);      //     262,144 B
  __bf16* h1   = (__bf16*)(p + 138674176ull);      //     262,144 B
  unsigned* cnt = (unsigned*)(p + 138936320ull);   //         256 B

  hipMemsetAsync(cnt, 0, 256, stream);

  k_cvt<<<dim3(2048), dim3(256), 0, stream>>>(x,   xb,   67108864 / 8);
  k_cvt<<<dim3(512),  dim3(256), 0, stream>>>(wih, wihb, 1572864 / 8);
  k_cvt<<<dim3(256),  dim3(256), 0, stream>>>(who, whob, 524288 / 8);

  k_rnn<<<dim3(64), dim3(256), 0, stream>>>(xb, wihb, bih, h0, h1, cnt);
  k_out<<<dim3(32), dim3(256), 0, stream>>>(h0, whob, bho, y);
}